// Round 26
// baseline (64.526 us; speedup 1.0000x reference)
//
#include <hip/hip_runtime.h>
#include <hip/hip_bf16.h>
#include <stdint.h>

// MHA B=1024,F=128,D=128,H=8,dh=16 fp32. Round 26: 2 head-pair iterations
// per block (grid 2048). afr (X fragments) loaded+converted ONCE, reused by
// both iterations (deletes 16 global loads + 16 pk2t + addressing per 2nd
// iter; halves dispatch count and X L2 traffic). proj(3) moved after
// attention (afr live anyway for iter 2 -> Ra's 16 regs leave the attention
// live set). kZero hoisted for all QK MFMA C-operands. Second barrier at
// iter-2 entry (drain iter-1 LDS reads). Else identical to R25 (no setprio,
// truncating packs, ones-column sums, exp2 builtin, permlane builtin).

typedef __attribute__((ext_vector_type(8))) short short8;
typedef __attribute__((ext_vector_type(16))) float f32x16;
typedef __attribute__((ext_vector_type(4))) unsigned int uint4v;
typedef __attribute__((ext_vector_type(2))) unsigned int uint2v;
typedef unsigned short ushort_t;
typedef unsigned int uint_t;

#define KF_OFF 0        // Kfrag[2h][4tt][swizzled 1KiB]  (8 KiB)
#define QF_OFF 8192     // Qfrag[2h][4w][swizzled 1KiB]   (8 KiB)
#define VT_OFF 16384    // Vt[2h][16e][128f] bf16, e-swizzled (8 KiB)
#define ONES_OFF 24576  // 256 B of bf16 1.0 (sum column)

__device__ __forceinline__ ushort_t b16(float f) {  // exact RNE (prep only)
  return __builtin_bit_cast(ushort_t, __float2bfloat16(f));
}
// truncating pack {lo: bf16t(a), hi: bf16t(b)} -- 1 VALU inst (v_perm_b32)
__device__ __forceinline__ uint_t pk2t(float a, float b) {
  return __byte_perm(__float_as_uint(a), __float_as_uint(b), 0x7632);
}
__device__ __forceinline__ ushort_t b16t(float f) {  // truncating scalar
  return (ushort_t)(__float_as_uint(f) >> 16);       // -> ds_write_b16_d16_hi
}

// ---- prep: weights fp32 -> bf16, 32x32x16 B-fragment order; cexp into Wq --
__global__ void prep_w(const float* __restrict__ Wq, const float* __restrict__ Wk,
                       const float* __restrict__ Wv, const float* __restrict__ Wr,
                       ushort_t* __restrict__ wt) {
  int i = blockIdx.x * 256 + threadIdx.x;  // 65536 total
  int u = i >> 9;
  int l = (i >> 3) & 63;
  int j = i & 7;
  int p = u >> 5, np = (u >> 3) & 3, kk = u & 7;
  int col = 32 * np + (l & 31);
  int d = kk * 16 + ((l >> 5) & 1) * 8 + j;
  const float* W = (p == 0) ? Wq : (p == 1) ? Wk : (p == 2) ? Wv : Wr;
  float scl = (p == 0) ? 0.12751459f : 1.0f;  // (1/sqrt(128))*log2(e) into Q
  wt[i] = b16(W[d * 128 + col] * scl);
}

// ---- main fused kernel -----------------------------------------------------
__global__ __launch_bounds__(256, 2) void mha26(const float* __restrict__ X,
                                                const ushort_t* __restrict__ wt,
                                                float* __restrict__ out) {
  __shared__ char lds[24832];
  const int t = threadIdx.x;
  const int w = t >> 6, l = t & 63;
  const int i = blockIdx.x;
  const int b = (i & 7) * 128 + (i >> 4);   // 2048 blocks; XCD-sibling swizzle
  const int hp = (i >> 3) & 1;              // head-pair select: hq = hp, hp+2
  const int hi5 = l >> 5, q = l & 31, e = l & 15, hb = (l >> 4) & 1;

  // ones block for the sum column (written before the first barrier)
  if (t < 16) {
    uint4v ones = {0x3F803F80u, 0x3F803F80u, 0x3F803F80u, 0x3F803F80u};
    *(uint4v*)(lds + ONES_OFF + t * 16) = ones;
  }

  // ---- A-fragments: wave's 32 X-rows, loaded + converted ONCE ----
  const float* xrow = X + (((size_t)b * 128) + 32 * w + q) * 128;
  short8 afr[8];
#pragma unroll
  for (int kk = 0; kk < 8; ++kk) {
    float4 a = *(const float4*)(xrow + kk * 16 + 8 * hi5);
    float4 c4 = *(const float4*)(xrow + kk * 16 + 8 * hi5 + 4);
    uint4v u = {pk2t(a.x, a.y), pk2t(a.z, a.w), pk2t(c4.x, c4.y), pk2t(c4.z, c4.w)};
    afr[kk] = __builtin_bit_cast(short8, u);
  }

  const short8* wf = (const short8*)wt;
  const f32x16 kZero = {};  // shared C-operand for all QK MFMAs

  // swizzle constants (iteration-invariant)
  const int sw0 = hi5 << 4;
  const int sw1 = (hi5 | 2) << 4;
  const char* vb0 = (q == 16) ? (lds + ONES_OFF) : (lds + VT_OFF);
  const char* vb1 = (q == 0) ? (lds + ONES_OFF) : (lds + VT_OFF + 4096);
  const int srcl = (l & 32) | (hb ? 0 : 16);

#pragma unroll
  for (int it = 0; it < 2; ++it) {
    const int hq = hp + 2 * it;           // heads {2hq, 2hq+1}

    auto proj = [&](int p) {
      f32x16 acc = {};
#pragma unroll
      for (int kk = 0; kk < 8; ++kk) {
        short8 bfr = wf[((p * 4 + hq) * 8 + kk) * 64 + l];
        acc = __builtin_amdgcn_mfma_f32_32x32x16_bf16(afr[kk], bfr, acc, 0, 0, 0);
      }
      return acc;
    };
    auto st_qk = [&](int off, const f32x16& d) {
      const int uxor = ((e >> 3) | (hb << 1));
      char* p = lds + off + hb * 4096 + w * 1024 + 512 * (e >> 3) +
                (e & 7) * 2 + 64 * hi5;
#pragma unroll
      for (int r = 0; r < 16; ++r) {
        int u = (r & 3) + 8 * (r >> 2);
        *(ushort_t*)(p + 16 * (u ^ uxor)) = b16t(d[r]);
      }
    };
    auto st_v = [&](const f32x16& d) {
#pragma unroll
      for (int q2 = 0; q2 < 4; ++q2) {
        int f0 = 32 * w + 8 * q2 + 4 * hi5;
        uint2v pk = {pk2t(d[4 * q2 + 0], d[4 * q2 + 1]),
                     pk2t(d[4 * q2 + 2], d[4 * q2 + 3])};
        *(uint2v*)(lds + VT_OFF + hb * 4096 + e * 256 +
                   ((f0 * 2) ^ ((e & 7) << 4))) = pk;
      }
    };

    if (it) __syncthreads();  // drain iter-1 LDS reads before restaging
    {
      f32x16 d;
      d = proj(0); st_qk(QF_OFF, d);   // Q (pre-scaled in weights)
      d = proj(1); st_qk(KF_OFF, d);
      d = proj(2); st_v(d);
    }
    __syncthreads();

    // ---- attention: both heads interleaved per 32-key tile ----
    short8 qf0 = *(const short8*)(lds + QF_OFF + w * 1024 + ((l * 16) ^ sw0));
    short8 qf1 = *(const short8*)(lds + QF_OFF + 4096 + w * 1024 +
                                  ((l * 16) ^ sw1));
    f32x16 oA = {}, oB = {};
    auto finish = [&](f32x16& s, f32x16& o, const char* vb, int tt) {
#pragma unroll
      for (int r = 0; r < 16; ++r) s[r] = __builtin_amdgcn_exp2f(s[r]);
#pragma unroll
      for (int gg = 0; gg < 2; ++gg) {
        int rb = gg * 8, g = 2 * tt + gg;
        uint_t wl  = pk2t(s[rb + 0], s[rb + 1]);
        uint_t wl2 = pk2t(s[rb + 2], s[rb + 3]);
        uint_t wh  = pk2t(s[rb + 4], s[rb + 5]);
        uint_t wh2 = pk2t(s[rb + 6], s[rb + 7]);
        uint2v r0 = __builtin_amdgcn_permlane32_swap(wl, wh, false, false);
        uint2v r1 = __builtin_amdgcn_permlane32_swap(wl2, wh2, false, false);
        uint4v pw = {r0[0], r1[0], r0[1], r1[1]};
        short8 pa = __builtin_bit_cast(short8, pw);
        short8 vfr = *(const short8*)(vb + e * 256 +
                                      ((32 * g + 16 * hi5) ^ ((e & 7) << 4)));
        o = __builtin_amdgcn_mfma_f32_32x32x16_bf16(pa, vfr, o, 0, 0, 0);
      }
    };

#pragma unroll
    for (int tt = 0; tt < 4; ++tt) {
      short8 kf0 = *(const short8*)(lds + KF_OFF + tt * 1024 + ((l * 16) ^ sw0));
      short8 kf1 = *(const short8*)(lds + KF_OFF + 4096 + tt * 1024 +
                                    ((l * 16) ^ sw1));
      f32x16 s0 = __builtin_amdgcn_mfma_f32_32x32x16_bf16(kf0, qf0, kZero, 0, 0, 0);
      f32x16 s1 = __builtin_amdgcn_mfma_f32_32x32x16_bf16(kf1, qf1, kZero, 0, 0, 0);
      finish(s0, oA, vb0, tt);
      finish(s1, oB, vb1, tt);
    }

    // residual projection late: afr is live anyway (iter 2), Ra live range
    // shrinks to the epilogue only.
    f32x16 Ra = proj(3);

    // epilogue: ones-column sums at lane q==16 (oA) / q==0 (oB), reg r.
#pragma unroll
    for (int r = 0; r < 16; ++r) {
      int row = (r & 3) + 8 * (r >> 2) + 4 * hi5;
      float d = (q == 16) ? oA[r] : oB[r];
      float s = __shfl(d, srcl, 64);
      float rsr = __builtin_amdgcn_rcpf(s);
      float ov = hb ? oB[r] : oA[r];
      float val = __builtin_fmaf(ov, rsr, Ra[r]);
      out[(((size_t)b * 128) + 32 * w + row) * 128 + 32 * hq + q] = val;
    }
  }
}

extern "C" void kernel_launch(void* const* d_in, const int* in_sizes, int n_in,
                              void* d_out, int out_size, void* d_ws, size_t ws_size,
                              hipStream_t stream) {
  const float* X  = (const float*)d_in[0];
  const float* Wq = (const float*)d_in[1];
  const float* Wk = (const float*)d_in[2];
  const float* Wv = (const float*)d_in[3];
  const float* Wr = (const float*)d_in[4];
  float* out = (float*)d_out;
  ushort_t* wt = (ushort_t*)d_ws;  // 128 KiB fragment-ordered bf16 weights

  hipLaunchKernelGGL(prep_w, dim3(256), dim3(256), 0, stream, Wq, Wk, Wv, Wr, wt);
  hipLaunchKernelGGL(mha26, dim3(2048), dim3(256), 0, stream, X, wt, out);
}

// Round 27
// 62.107 us; speedup vs baseline: 1.0390x; 1.0390x over previous
//
#include <hip/hip_runtime.h>
#include <hip/hip_bf16.h>
#include <stdint.h>

// MHA B=1024,F=128,D=128,H=8,dh=16 fp32. Round 27: FINAL — byte-identical
// restore of R23 (62.1us, session best). R26's 2-iter work-reuse regressed
// (occupancy 28->18%, latency-hiding loss > staging savings), consistent
// with the session-long finding: this kernel is dependency-latency-bound at
// AGPR-capped ~2 blocks/CU, with no pipe saturated (HBM 16%, MFMA 18%,
// VALU 31%). All levers measured: occupancy up/down, interleave, phase-move,
// setprio, VALU diet — plateau bracketed at 62 +/- 1us from every direction.
// Structure: 4096 blocks = (batch, head-quarter), 256 thr, 24.25 KiB LDS,
// (256,2); fused proj (Q/K/V via one A-frag set, R in regs) -> swapped-QK^T
// attention (lane-local softmax, no max-sub — |cexp*S|<=~1), ones-column
// MFMA softmax-denominator, in-register P via truncating byte_perm pack +
// permlane32_swap builtin, exp2 builtin, one barrier, fp32 epilogue.

typedef __attribute__((ext_vector_type(8))) short short8;
typedef __attribute__((ext_vector_type(16))) float f32x16;
typedef __attribute__((ext_vector_type(4))) unsigned int uint4v;
typedef __attribute__((ext_vector_type(2))) unsigned int uint2v;
typedef unsigned short ushort_t;
typedef unsigned int uint_t;

#define KF_OFF 0        // Kfrag[2h][4tt][swizzled 1KiB]  (8 KiB)
#define QF_OFF 8192     // Qfrag[2h][4w][swizzled 1KiB]   (8 KiB)
#define VT_OFF 16384    // Vt[2h][16e][128f] bf16, e-swizzled (8 KiB)
#define ONES_OFF 24576  // 256 B of bf16 1.0 (sum column)

__device__ __forceinline__ ushort_t b16(float f) {  // exact RNE (prep only)
  return __builtin_bit_cast(ushort_t, __float2bfloat16(f));
}
// truncating pack {lo: bf16t(a), hi: bf16t(b)} -- 1 VALU inst (v_perm_b32)
__device__ __forceinline__ uint_t pk2t(float a, float b) {
  return __byte_perm(__float_as_uint(a), __float_as_uint(b), 0x7632);
}
__device__ __forceinline__ ushort_t b16t(float f) {  // truncating scalar
  return (ushort_t)(__float_as_uint(f) >> 16);       // -> ds_write_b16_d16_hi
}

// ---- prep: weights fp32 -> bf16, 32x32x16 B-fragment order; cexp into Wq --
__global__ void prep_w(const float* __restrict__ Wq, const float* __restrict__ Wk,
                       const float* __restrict__ Wv, const float* __restrict__ Wr,
                       ushort_t* __restrict__ wt) {
  int i = blockIdx.x * 256 + threadIdx.x;  // 65536 total
  int u = i >> 9;
  int l = (i >> 3) & 63;
  int j = i & 7;
  int p = u >> 5, np = (u >> 3) & 3, kk = u & 7;
  int col = 32 * np + (l & 31);
  int d = kk * 16 + ((l >> 5) & 1) * 8 + j;
  const float* W = (p == 0) ? Wq : (p == 1) ? Wk : (p == 2) ? Wv : Wr;
  float scl = (p == 0) ? 0.12751459f : 1.0f;  // (1/sqrt(128))*log2(e) into Q
  wt[i] = b16(W[d * 128 + col] * scl);
}

// ---- main fused kernel -----------------------------------------------------
__global__ __launch_bounds__(256, 2) void mha27(const float* __restrict__ X,
                                                const ushort_t* __restrict__ wt,
                                                float* __restrict__ out) {
  __shared__ char lds[24832];
  const int t = threadIdx.x;
  const int w = t >> 6, l = t & 63;
  const int i = blockIdx.x;
  const int b = (i & 7) * 128 + (i >> 5);   // XCD-sibling swizzle
  const int hq = (i >> 3) & 3;              // heads {2hq, 2hq+1}
  const int hi5 = l >> 5, q = l & 31, e = l & 15, hb = (l >> 4) & 1;

  // ones block for the sum column (written before the barrier)
  if (t < 16) {
    uint4v ones = {0x3F803F80u, 0x3F803F80u, 0x3F803F80u, 0x3F803F80u};
    *(uint4v*)(lds + ONES_OFF + t * 16) = ones;
  }

  // ---- A-fragments: wave's 32 X-rows direct from global, fp32 -> bf16 ----
  const float* xrow = X + (((size_t)b * 128) + 32 * w + q) * 128;
  short8 afr[8];
#pragma unroll
  for (int kk = 0; kk < 8; ++kk) {
    float4 a = *(const float4*)(xrow + kk * 16 + 8 * hi5);
    float4 c4 = *(const float4*)(xrow + kk * 16 + 8 * hi5 + 4);
    uint4v u = {pk2t(a.x, a.y), pk2t(a.z, a.w), pk2t(c4.x, c4.y), pk2t(c4.z, c4.w)};
    afr[kk] = __builtin_bit_cast(short8, u);
  }

  const short8* wf = (const short8*)wt;
  auto proj = [&](int p) {
    f32x16 acc = {};
#pragma unroll
    for (int kk = 0; kk < 8; ++kk) {
      short8 bfr = wf[((p * 4 + hq) * 8 + kk) * 64 + l];
      acc = __builtin_amdgcn_mfma_f32_32x32x16_bf16(afr[kk], bfr, acc, 0, 0, 0);
    }
    return acc;
  };
  // store D into fragment order with bank swizzle (R9-proven)
  auto st_qk = [&](int off, const f32x16& d) {
    const int uxor = ((e >> 3) | (hb << 1));
    char* p = lds + off + hb * 4096 + w * 1024 + 512 * (e >> 3) +
              (e & 7) * 2 + 64 * hi5;
#pragma unroll
    for (int r = 0; r < 16; ++r) {
      int u = (r & 3) + 8 * (r >> 2);
      *(ushort_t*)(p + 16 * (u ^ uxor)) = b16t(d[r]);
    }
  };
  auto st_v = [&](const f32x16& d) {  // transposed Vt[e][f], packed 8B
#pragma unroll
    for (int q2 = 0; q2 < 4; ++q2) {
      int f0 = 32 * w + 8 * q2 + 4 * hi5;
      uint2v pk = {pk2t(d[4 * q2 + 0], d[4 * q2 + 1]),
                   pk2t(d[4 * q2 + 2], d[4 * q2 + 3])};
      *(uint2v*)(lds + VT_OFF + hb * 4096 + e * 256 +
                 ((f0 * 2) ^ ((e & 7) << 4))) = pk;
    }
  };

  f32x16 Ra;
  {
    f32x16 d;
    d = proj(0); st_qk(QF_OFF, d);   // Q (pre-scaled in weights)
    d = proj(1); st_qk(KF_OFF, d);
    d = proj(2); st_v(d);
    Ra = proj(3);
  }
  __syncthreads();  // only barrier

  // ---- attention: both heads interleaved per 32-key tile ----
  const int sw0 = hi5 << 4;         // read-side swizzle, head 0
  const int sw1 = (hi5 | 2) << 4;   // head 1
  short8 qf0 = *(const short8*)(lds + QF_OFF + w * 1024 + ((l * 16) ^ sw0));
  short8 qf1 = *(const short8*)(lds + QF_OFF + 4096 + w * 1024 +
                                ((l * 16) ^ sw1));
  // V base: the lane one past the used half reads the ones column instead
  // (its e is 0, so the swizzle term vanishes and addr = ONES_OFF+32g+16hi5)
  const char* vb0 = (q == 16) ? (lds + ONES_OFF) : (lds + VT_OFF);
  const char* vb1 = (q == 0) ? (lds + ONES_OFF) : (lds + VT_OFF + 4096);

  f32x16 oA = {}, oB = {};
  // softmax-finish + PV for one head's 32-key tile (truncating P pack)
  auto finish = [&](f32x16& s, f32x16& o, const char* vb, int tt) {
#pragma unroll
    for (int r = 0; r < 16; ++r) s[r] = __builtin_amdgcn_exp2f(s[r]);
#pragma unroll
    for (int gg = 0; gg < 2; ++gg) {
      int rb = gg * 8, g = 2 * tt + gg;
      uint_t wl  = pk2t(s[rb + 0], s[rb + 1]);
      uint_t wl2 = pk2t(s[rb + 2], s[rb + 3]);
      uint_t wh  = pk2t(s[rb + 4], s[rb + 5]);
      uint_t wh2 = pk2t(s[rb + 6], s[rb + 7]);
      uint2v r0 = __builtin_amdgcn_permlane32_swap(wl, wh, false, false);
      uint2v r1 = __builtin_amdgcn_permlane32_swap(wl2, wh2, false, false);
      uint4v pw = {r0[0], r1[0], r0[1], r1[1]};
      short8 pa = __builtin_bit_cast(short8, pw);
      short8 vfr = *(const short8*)(vb + e * 256 +
                                    ((32 * g + 16 * hi5) ^ ((e & 7) << 4)));
      __builtin_amdgcn_s_setprio(1);
      o = __builtin_amdgcn_mfma_f32_32x32x16_bf16(pa, vfr, o, 0, 0, 0);
      __builtin_amdgcn_s_setprio(0);
    }
  };

#pragma unroll
  for (int tt = 0; tt < 4; ++tt) {
    short8 kf0 = *(const short8*)(lds + KF_OFF + tt * 1024 + ((l * 16) ^ sw0));
    short8 kf1 = *(const short8*)(lds + KF_OFF + 4096 + tt * 1024 +
                                  ((l * 16) ^ sw1));
    f32x16 z0 = {}, z1 = {};
    __builtin_amdgcn_s_setprio(1);
    f32x16 s0 = __builtin_amdgcn_mfma_f32_32x32x16_bf16(kf0, qf0, z0, 0, 0, 0);
    f32x16 s1 = __builtin_amdgcn_mfma_f32_32x32x16_bf16(kf1, qf1, z1, 0, 0, 0);
    __builtin_amdgcn_s_setprio(0);
    finish(s0, oA, vb0, tt);   // h0 VALU chain overlaps h1's MFMA
    finish(s1, oB, vb1, tt);   // h1 VALU chain overlaps h0's PV MFMAs
  }

  // epilogue: per-row sums live in the ones columns (lane q==16 of oA,
  // lane q==0 of oB) at the SAME reg index r. Merge: d holds the sum value
  // on those lanes; one variable-lane shfl fetches own head's sum.
  const int srcl = (l & 32) | (hb ? 0 : 16);
#pragma unroll
  for (int r = 0; r < 16; ++r) {
    int row = (r & 3) + 8 * (r >> 2) + 4 * hi5;
    float d = (q == 16) ? oA[r] : oB[r];
    float s = __shfl(d, srcl, 64);
    float rsr = __builtin_amdgcn_rcpf(s);
    float ov = hb ? oB[r] : oA[r];
    float val = __builtin_fmaf(ov, rsr, Ra[r]);
    out[(((size_t)b * 128) + 32 * w + row) * 128 + 32 * hq + q] = val;
  }
}

extern "C" void kernel_launch(void* const* d_in, const int* in_sizes, int n_in,
                              void* d_out, int out_size, void* d_ws, size_t ws_size,
                              hipStream_t stream) {
  const float* X  = (const float*)d_in[0];
  const float* Wq = (const float*)d_in[1];
  const float* Wk = (const float*)d_in[2];
  const float* Wv = (const float*)d_in[3];
  const float* Wr = (const float*)d_in[4];
  float* out = (float*)d_out;
  ushort_t* wt = (ushort_t*)d_ws;  // 128 KiB fragment-ordered bf16 weights

  hipLaunchKernelGGL(prep_w, dim3(256), dim3(256), 0, stream, Wq, Wk, Wv, Wr, wt);
  hipLaunchKernelGGL(mha27, dim3(4096), dim3(256), 0, stream, X, wt, out);
}